// Round 11
// baseline (389.743 us; speedup 1.0000x reference)
//
#include <hip/hip_runtime.h>
#include <math.h>

#define N_ENT  50000
#define N_REL  500
#define N_EDGE 800000
#define D      100
#define ALPHA  0.2f

// ---------------------------------------------------------------------------
// K1: Y = X @ W for BOTH ent and rel in one launch.
// Blocks [0,1000): entity rows; blocks [1000,1010): relation rows.
// W^T staged in LDS at stride 101 (conflict-free); X tile in LDS.
// ---------------------------------------------------------------------------
#define PROJ_TPB  256
#define PROJ_RPB  50
#define PROJ_RPT  25
#define WT_STRIDE 101
#define ENT_BLKS  (N_ENT / PROJ_RPB)          // 1000
#define REL_BLKS  (N_REL / PROJ_RPB)          // 10

__global__ __launch_bounds__(PROJ_TPB) void proj_kernel(const float* __restrict__ Xe,
                                                        const float* __restrict__ Xr,
                                                        const float* __restrict__ W,
                                                        float* __restrict__ Ye,
                                                        float* __restrict__ Yr) {
    __shared__ float WT[D * WT_STRIDE];   // 40.4 KB
    __shared__ float Xs[PROJ_RPB * D];    // 20 KB
    int t = threadIdx.x;

    const float* X; float* Y; size_t xbase;
    if (blockIdx.x < ENT_BLKS) {
        X = Xe; Y = Ye; xbase = (size_t)blockIdx.x * PROJ_RPB * D;
    } else {
        X = Xr; Y = Yr; xbase = (size_t)(blockIdx.x - ENT_BLKS) * PROJ_RPB * D;
    }

    for (int i = t; i < D * D; i += PROJ_TPB) {
        int k = i / D, c = i % D;
        WT[c * WT_STRIDE + k] = W[i];
    }
    for (int i = t; i < PROJ_RPB * D; i += PROJ_TPB)
        Xs[i] = X[xbase + i];
    __syncthreads();

    if (t < 200) {
        int c  = t % 100;
        int r0 = (t / 100) * PROJ_RPT;
        const float* wt = &WT[c * WT_STRIDE];
        for (int j = 0; j < PROJ_RPT; j += 5) {
            const float* x0 = &Xs[(r0 + j    ) * D];
            const float* x1 = &Xs[(r0 + j + 1) * D];
            const float* x2 = &Xs[(r0 + j + 2) * D];
            const float* x3 = &Xs[(r0 + j + 3) * D];
            const float* x4 = &Xs[(r0 + j + 4) * D];
            float a0 = 0.f, a1 = 0.f, a2 = 0.f, a3 = 0.f, a4 = 0.f;
            #pragma unroll
            for (int k = 0; k < D; ++k) {
                float w = wt[k];
                a0 = fmaf(x0[k], w, a0);
                a1 = fmaf(x1[k], w, a1);
                a2 = fmaf(x2[k], w, a2);
                a3 = fmaf(x3[k], w, a3);
                a4 = fmaf(x4[k], w, a4);
            }
            Y[xbase + (size_t)(r0 + j    ) * D + c] = a0;
            Y[xbase + (size_t)(r0 + j + 1) * D + c] = a1;
            Y[xbase + (size_t)(r0 + j + 2) * D + c] = a2;
            Y[xbase + (size_t)(r0 + j + 3) * D + c] = a3;
            Y[xbase + (size_t)(r0 + j + 4) * D + c] = a4;
        }
    }
}

// ---------------------------------------------------------------------------
// degree count (atomics)
// ---------------------------------------------------------------------------
__global__ void degree_kernel(const int* __restrict__ h_idx, int* __restrict__ deg) {
    int e = blockIdx.x * blockDim.x + threadIdx.x;
    if (e < N_EDGE) atomicAdd(&deg[h_idx[e]], 1);
}

// ---------------------------------------------------------------------------
// Single-block exclusive scan over deg[0..N_ENT) -> rowptr, cursor.
// 1024 threads x 49 elements each (1024*49 = 50176 >= 50000).
// ---------------------------------------------------------------------------
#define SCAN_T   1024
#define SCAN_EPT 49
__global__ __launch_bounds__(SCAN_T) void scan_kernel(const int* __restrict__ deg,
                                                      int* __restrict__ rowptr,
                                                      int* __restrict__ cursor) {
    __shared__ int s[SCAN_T];
    int tid  = threadIdx.x;
    int base = tid * SCAN_EPT;

    int local = 0;
    #pragma unroll 7
    for (int j = 0; j < SCAN_EPT; ++j) {
        int i = base + j;
        if (i < N_ENT) local += deg[i];
    }
    s[tid] = local;
    __syncthreads();
    // Hillis-Steele inclusive scan over 1024 partials
    for (int off = 1; off < SCAN_T; off <<= 1) {
        int x = (tid >= off) ? s[tid - off] : 0;
        __syncthreads();
        s[tid] += x;
        __syncthreads();
    }
    int excl = s[tid] - local;          // exclusive prefix of this thread's chunk
    #pragma unroll 7
    for (int j = 0; j < SCAN_EPT; ++j) {
        int i = base + j;
        if (i < N_ENT) {
            rowptr[i] = excl;
            cursor[i] = excl;
            excl += deg[i];
        }
    }
    if (tid == SCAN_T - 1) rowptr[N_ENT] = s[SCAN_T - 1];
}

// ---------------------------------------------------------------------------
// fill buckets (atomic cursor)
// ---------------------------------------------------------------------------
__global__ void fill_kernel(const int* __restrict__ h_idx, const int* __restrict__ t_idx,
                            const int* __restrict__ etype, int* __restrict__ cursor,
                            int2* __restrict__ tr_sorted) {
    int e = blockIdx.x * blockDim.x + threadIdx.x;
    if (e >= N_EDGE) return;
    int h = h_idx[e];
    int pos = atomicAdd(&cursor[h], 1);
    tr_sorted[pos] = make_int2(t_idx[e], etype[e]);
}

// ---------------------------------------------------------------------------
// Fused kernel: one head per 32-lane half-wave, float4 per lane (25 active),
// online softmax, UNROLL-4: 4 edges' gathers issue before any serial chain.
// ---------------------------------------------------------------------------
__device__ __forceinline__ float edge_reduce32(const float4& eh, const float4& v) {
    float dx = eh.x + v.x, dy = eh.y + v.y, dz = eh.z + v.z, dw = eh.w + v.w;
    float s = dx * dx;
    s = fmaf(dy, dy, s);
    s = fmaf(dz, dz, s);
    s = fmaf(dw, dw, s);
    #pragma unroll
    for (int off = 16; off; off >>= 1) s += __shfl_xor(s, off, 32);
    return sqrtf(s);                       // leaky_relu identity (s >= 0)
}

__global__ __launch_bounds__(256) void fused_kernel(const float* __restrict__ ent,
                                                    const float* __restrict__ rel,
                                                    const int* __restrict__ rowptr,
                                                    const int2* __restrict__ tr_sorted,
                                                    float* __restrict__ out) {
    int head = blockIdx.x * 8 + (threadIdx.x >> 5);   // 8 half-waves per block
    int lane = threadIdx.x & 31;
    if (head >= N_ENT) return;                        // grid exact: 6250*8
    int beg = rowptr[head], end = rowptr[head + 1];

    float4 eh = make_float4(0.f, 0.f, 0.f, 0.f);
    if (lane < 25) eh = ((const float4*)(ent + (size_t)head * D))[lane];

    float  m   = -INFINITY;
    float  den = 0.f;
    float4 acc = make_float4(0.f, 0.f, 0.f, 0.f);

    int i = beg;
    for (; i + 3 < end; i += 4) {
        int2 ee[4];
        float4 vv[4];
        #pragma unroll
        for (int u = 0; u < 4; ++u) ee[u] = tr_sorted[i + u];
        #pragma unroll
        for (int u = 0; u < 4; ++u) {
            float4 v = make_float4(0.f, 0.f, 0.f, 0.f);
            if (lane < 25) {
                float4 et = ((const float4*)(ent + (size_t)ee[u].x * D))[lane];
                float4 er = ((const float4*)(rel + (size_t)ee[u].y * D))[lane];
                v = make_float4(er.x - et.x, er.y - et.y, er.z - et.z, er.w - et.w);
            }
            vv[u] = v;
        }
        float sc[4];
        #pragma unroll
        for (int u = 0; u < 4; ++u) sc[u] = edge_reduce32(eh, vv[u]);
        #pragma unroll
        for (int u = 0; u < 4; ++u) {
            float mn    = fmaxf(m, sc[u]);
            float scale = __expf(m - mn);
            float ex    = __expf(sc[u] - mn);
            den   = den * scale + ex;
            acc.x = acc.x * scale - vv[u].x * ex;
            acc.y = acc.y * scale - vv[u].y * ex;
            acc.z = acc.z * scale - vv[u].z * ex;
            acc.w = acc.w * scale - vv[u].w * ex;
            m = mn;
        }
    }
    for (; i < end; ++i) {
        int2 e0 = tr_sorted[i];
        float4 v = make_float4(0.f, 0.f, 0.f, 0.f);
        if (lane < 25) {
            float4 et = ((const float4*)(ent + (size_t)e0.x * D))[lane];
            float4 er = ((const float4*)(rel + (size_t)e0.y * D))[lane];
            v = make_float4(er.x - et.x, er.y - et.y, er.z - et.z, er.w - et.w);
        }
        float sc = edge_reduce32(eh, v);
        float mn    = fmaxf(m, sc);
        float scale = __expf(m - mn);
        float ex    = __expf(sc - mn);
        den   = den * scale + ex;
        acc.x = acc.x * scale - v.x * ex;
        acc.y = acc.y * scale - v.y * ex;
        acc.z = acc.z * scale - v.z * ex;
        acc.w = acc.w * scale - v.w * ex;
        m = mn;
    }

    float inv = 1.f / (den + 1e-16f);
    float ox = acc.x * inv, oy = acc.y * inv, oz = acc.z * inv, ow = acc.w * inv;
    ox = ox > 0.f ? ox : expm1f(ox);           // ELU
    oy = oy > 0.f ? oy : expm1f(oy);
    oz = oz > 0.f ? oz : expm1f(oz);
    ow = ow > 0.f ? ow : expm1f(ow);
    if (lane < 25)
        ((float4*)(out + (size_t)head * D))[lane] = make_float4(ox, oy, oz, ow);
}

extern "C" void kernel_launch(void* const* d_in, const int* in_sizes, int n_in,
                              void* d_out, int out_size, void* d_ws, size_t ws_size,
                              hipStream_t stream) {
    const float* entity_emb = (const float*)d_in[0];   // [N_ENT, D]
    const float* rel_emb    = (const float*)d_in[1];   // [N_REL, D]
    const float* W          = (const float*)d_in[2];   // [D, D]
    const int*   edge_index = (const int*)d_in[3];     // [2, N_EDGE]
    const int*   edge_type  = (const int*)d_in[4];     // [N_EDGE]
    float*       out        = (float*)d_out;           // [N_ENT, D]

    const int* h_idx = edge_index;             // row 0: head/destination
    const int* t_idx = edge_index + N_EDGE;    // row 1: tail/source

    // workspace layout (~27 MB)
    float* ent       = (float*)d_ws;                    // 5,000,000 f
    float* rel       = ent + (size_t)N_ENT * D;         //    50,000 f
    int*   deg       = (int*)(rel + (size_t)N_REL * D); //    50,000 i
    int*   rowptr    = deg + N_ENT;                     //    50,001 i
    int*   cursor    = rowptr + (N_ENT + 1);            //    50,000 i
    int2*  tr_sorted = (int2*)(cursor + N_ENT);         //   800,000 int2

    hipMemsetAsync(deg, 0, N_ENT * sizeof(int), stream);

    // projections (ent + rel in one launch)
    proj_kernel<<<ENT_BLKS + REL_BLKS, PROJ_TPB, 0, stream>>>(entity_emb, rel_emb,
                                                              W, ent, rel);

    // CSR build: degree -> single-block scan -> fill
    degree_kernel<<<(N_EDGE + 255) / 256, 256, 0, stream>>>(h_idx, deg);
    scan_kernel<<<1, SCAN_T, 0, stream>>>(deg, rowptr, cursor);
    fill_kernel<<<(N_EDGE + 255) / 256, 256, 0, stream>>>(h_idx, t_idx, edge_type,
                                                          cursor, tr_sorted);

    // fused: one head per 32-lane half-wave (8 heads / 256-thread block)
    fused_kernel<<<N_ENT / 8, 256, 0, stream>>>(ent, rel, rowptr, tr_sorted, out);
}

// Round 12
// 265.974 us; speedup vs baseline: 1.4653x; 1.4653x over previous
//
#include <hip/hip_runtime.h>
#include <math.h>

#define N_ENT  50000
#define N_REL  500
#define N_EDGE 800000
#define D      100
#define ALPHA  0.2f

#define SCAN_B 256
#define NBLK_SCAN ((N_ENT + SCAN_B - 1) / SCAN_B)   // 196

// ---------------------------------------------------------------------------
// K1: Y = X @ W for BOTH ent and rel in one launch.
// Blocks [0,1000): entity rows; blocks [1000,1010): relation rows.
// W^T staged in LDS at stride 101 (conflict-free); X tile in LDS.
// ---------------------------------------------------------------------------
#define PROJ_TPB  256
#define PROJ_RPB  50
#define PROJ_RPT  25
#define WT_STRIDE 101
#define ENT_BLKS  (N_ENT / PROJ_RPB)          // 1000
#define REL_BLKS  (N_REL / PROJ_RPB)          // 10

__global__ __launch_bounds__(PROJ_TPB) void proj_kernel(const float* __restrict__ Xe,
                                                        const float* __restrict__ Xr,
                                                        const float* __restrict__ W,
                                                        float* __restrict__ Ye,
                                                        float* __restrict__ Yr) {
    __shared__ float WT[D * WT_STRIDE];   // 40.4 KB
    __shared__ float Xs[PROJ_RPB * D];    // 20 KB
    int t = threadIdx.x;

    const float* X; float* Y; size_t xbase;
    if (blockIdx.x < ENT_BLKS) {
        X = Xe; Y = Ye; xbase = (size_t)blockIdx.x * PROJ_RPB * D;
    } else {
        X = Xr; Y = Yr; xbase = (size_t)(blockIdx.x - ENT_BLKS) * PROJ_RPB * D;
    }

    for (int i = t; i < D * D; i += PROJ_TPB) {
        int k = i / D, c = i % D;
        WT[c * WT_STRIDE + k] = W[i];
    }
    for (int i = t; i < PROJ_RPB * D; i += PROJ_TPB)
        Xs[i] = X[xbase + i];
    __syncthreads();

    if (t < 200) {
        int c  = t % 100;
        int r0 = (t / 100) * PROJ_RPT;
        const float* wt = &WT[c * WT_STRIDE];
        for (int j = 0; j < PROJ_RPT; j += 5) {
            const float* x0 = &Xs[(r0 + j    ) * D];
            const float* x1 = &Xs[(r0 + j + 1) * D];
            const float* x2 = &Xs[(r0 + j + 2) * D];
            const float* x3 = &Xs[(r0 + j + 3) * D];
            const float* x4 = &Xs[(r0 + j + 4) * D];
            float a0 = 0.f, a1 = 0.f, a2 = 0.f, a3 = 0.f, a4 = 0.f;
            #pragma unroll
            for (int k = 0; k < D; ++k) {
                float w = wt[k];
                a0 = fmaf(x0[k], w, a0);
                a1 = fmaf(x1[k], w, a1);
                a2 = fmaf(x2[k], w, a2);
                a3 = fmaf(x3[k], w, a3);
                a4 = fmaf(x4[k], w, a4);
            }
            Y[xbase + (size_t)(r0 + j    ) * D + c] = a0;
            Y[xbase + (size_t)(r0 + j + 1) * D + c] = a1;
            Y[xbase + (size_t)(r0 + j + 2) * D + c] = a2;
            Y[xbase + (size_t)(r0 + j + 3) * D + c] = a3;
            Y[xbase + (size_t)(r0 + j + 4) * D + c] = a4;
        }
    }
}

// ---------------------------------------------------------------------------
// CSR build: degree count -> 3-kernel parallel scan -> fill buckets
// ---------------------------------------------------------------------------
__global__ void degree_kernel(const int* __restrict__ h_idx, int* __restrict__ deg) {
    int e = blockIdx.x * blockDim.x + threadIdx.x;
    if (e < N_EDGE) atomicAdd(&deg[h_idx[e]], 1);
}

__global__ void scan1_kernel(const int* __restrict__ deg, int* __restrict__ bsum) {
    __shared__ int s[SCAN_B];
    int i = blockIdx.x * SCAN_B + threadIdx.x;
    s[threadIdx.x] = (i < N_ENT) ? deg[i] : 0;
    __syncthreads();
    for (int off = SCAN_B / 2; off; off >>= 1) {
        if (threadIdx.x < off) s[threadIdx.x] += s[threadIdx.x + off];
        __syncthreads();
    }
    if (threadIdx.x == 0) bsum[blockIdx.x] = s[0];
}

__global__ void scan2_kernel(const int* __restrict__ bsum, int* __restrict__ boff) {
    __shared__ int s[SCAN_B];
    int tid = threadIdx.x;
    int v = (tid < NBLK_SCAN) ? bsum[tid] : 0;
    s[tid] = v;
    __syncthreads();
    for (int off = 1; off < SCAN_B; off <<= 1) {
        int x = (tid >= off) ? s[tid - off] : 0;
        __syncthreads();
        s[tid] += x;
        __syncthreads();
    }
    if (tid < NBLK_SCAN) boff[tid] = s[tid] - v;   // exclusive
}

__global__ void scan3_kernel(const int* __restrict__ deg, const int* __restrict__ boff,
                             int* __restrict__ rowptr, int* __restrict__ cursor) {
    __shared__ int s[SCAN_B];
    int tid = threadIdx.x;
    int i = blockIdx.x * SCAN_B + tid;
    int v = (i < N_ENT) ? deg[i] : 0;
    s[tid] = v;
    __syncthreads();
    for (int off = 1; off < SCAN_B; off <<= 1) {
        int x = (tid >= off) ? s[tid - off] : 0;
        __syncthreads();
        s[tid] += x;
        __syncthreads();
    }
    int excl = s[tid] - v + boff[blockIdx.x];
    if (i < N_ENT) { rowptr[i] = excl; cursor[i] = excl; }
    if (i == N_ENT - 1) rowptr[N_ENT] = excl + v;
}

__global__ void fill_kernel(const int* __restrict__ h_idx, const int* __restrict__ t_idx,
                            const int* __restrict__ etype, int* __restrict__ cursor,
                            int2* __restrict__ tr_sorted) {
    int e = blockIdx.x * blockDim.x + threadIdx.x;
    if (e >= N_EDGE) return;
    int h = h_idx[e];
    int pos = atomicAdd(&cursor[h], 1);
    tr_sorted[pos] = make_int2(t_idx[e], etype[e]);
}

// ---------------------------------------------------------------------------
// Fused kernel: one head per 32-lane half-wave, float4 per lane (25 active),
// online softmax, UNROLL-4: 4 edges' gathers issue before any serial chain.
// ---------------------------------------------------------------------------
__device__ __forceinline__ float edge_reduce32(const float4& eh, const float4& v) {
    float dx = eh.x + v.x, dy = eh.y + v.y, dz = eh.z + v.z, dw = eh.w + v.w;
    float s = dx * dx;
    s = fmaf(dy, dy, s);
    s = fmaf(dz, dz, s);
    s = fmaf(dw, dw, s);
    #pragma unroll
    for (int off = 16; off; off >>= 1) s += __shfl_xor(s, off, 32);
    return sqrtf(s);                       // leaky_relu identity (s >= 0)
}

__global__ __launch_bounds__(256) void fused_kernel(const float* __restrict__ ent,
                                                    const float* __restrict__ rel,
                                                    const int* __restrict__ rowptr,
                                                    const int2* __restrict__ tr_sorted,
                                                    float* __restrict__ out) {
    int head = blockIdx.x * 8 + (threadIdx.x >> 5);   // 8 half-waves per block
    int lane = threadIdx.x & 31;
    if (head >= N_ENT) return;                        // grid exact: 6250*8
    int beg = rowptr[head], end = rowptr[head + 1];

    float4 eh = make_float4(0.f, 0.f, 0.f, 0.f);
    if (lane < 25) eh = ((const float4*)(ent + (size_t)head * D))[lane];

    float  m   = -INFINITY;
    float  den = 0.f;
    float4 acc = make_float4(0.f, 0.f, 0.f, 0.f);

    int i = beg;
    for (; i + 3 < end; i += 4) {
        int2 ee[4];
        float4 vv[4];
        #pragma unroll
        for (int u = 0; u < 4; ++u) ee[u] = tr_sorted[i + u];
        #pragma unroll
        for (int u = 0; u < 4; ++u) {
            float4 v = make_float4(0.f, 0.f, 0.f, 0.f);
            if (lane < 25) {
                float4 et = ((const float4*)(ent + (size_t)ee[u].x * D))[lane];
                float4 er = ((const float4*)(rel + (size_t)ee[u].y * D))[lane];
                v = make_float4(er.x - et.x, er.y - et.y, er.z - et.z, er.w - et.w);
            }
            vv[u] = v;
        }
        float sc[4];
        #pragma unroll
        for (int u = 0; u < 4; ++u) sc[u] = edge_reduce32(eh, vv[u]);
        #pragma unroll
        for (int u = 0; u < 4; ++u) {
            float mn    = fmaxf(m, sc[u]);
            float scale = __expf(m - mn);
            float ex    = __expf(sc[u] - mn);
            den   = den * scale + ex;
            acc.x = acc.x * scale - vv[u].x * ex;
            acc.y = acc.y * scale - vv[u].y * ex;
            acc.z = acc.z * scale - vv[u].z * ex;
            acc.w = acc.w * scale - vv[u].w * ex;
            m = mn;
        }
    }
    for (; i < end; ++i) {
        int2 e0 = tr_sorted[i];
        float4 v = make_float4(0.f, 0.f, 0.f, 0.f);
        if (lane < 25) {
            float4 et = ((const float4*)(ent + (size_t)e0.x * D))[lane];
            float4 er = ((const float4*)(rel + (size_t)e0.y * D))[lane];
            v = make_float4(er.x - et.x, er.y - et.y, er.z - et.z, er.w - et.w);
        }
        float sc = edge_reduce32(eh, v);
        float mn    = fmaxf(m, sc);
        float scale = __expf(m - mn);
        float ex    = __expf(sc - mn);
        den   = den * scale + ex;
        acc.x = acc.x * scale - v.x * ex;
        acc.y = acc.y * scale - v.y * ex;
        acc.z = acc.z * scale - v.z * ex;
        acc.w = acc.w * scale - v.w * ex;
        m = mn;
    }

    float inv = 1.f / (den + 1e-16f);
    float ox = acc.x * inv, oy = acc.y * inv, oz = acc.z * inv, ow = acc.w * inv;
    ox = ox > 0.f ? ox : expm1f(ox);           // ELU
    oy = oy > 0.f ? oy : expm1f(oy);
    oz = oz > 0.f ? oz : expm1f(oz);
    ow = ow > 0.f ? ow : expm1f(ow);
    if (lane < 25)
        ((float4*)(out + (size_t)head * D))[lane] = make_float4(ox, oy, oz, ow);
}

extern "C" void kernel_launch(void* const* d_in, const int* in_sizes, int n_in,
                              void* d_out, int out_size, void* d_ws, size_t ws_size,
                              hipStream_t stream) {
    const float* entity_emb = (const float*)d_in[0];   // [N_ENT, D]
    const float* rel_emb    = (const float*)d_in[1];   // [N_REL, D]
    const float* W          = (const float*)d_in[2];   // [D, D]
    const int*   edge_index = (const int*)d_in[3];     // [2, N_EDGE]
    const int*   edge_type  = (const int*)d_in[4];     // [N_EDGE]
    float*       out        = (float*)d_out;           // [N_ENT, D]

    const int* h_idx = edge_index;             // row 0: head/destination
    const int* t_idx = edge_index + N_EDGE;    // row 1: tail/source

    // workspace layout (~27 MB)
    float* ent       = (float*)d_ws;                    // 5,000,000 f
    float* rel       = ent + (size_t)N_ENT * D;         //    50,000 f
    int*   deg       = (int*)(rel + (size_t)N_REL * D); //    50,000 i
    int*   rowptr    = deg + N_ENT;                     //    50,001 i
    int*   cursor    = rowptr + (N_ENT + 1);            //    50,000 i
    int*   bsum      = cursor + N_ENT;                  //       256 i
    int*   boff      = bsum + SCAN_B;                   //       256 i
    int2*  tr_sorted = (int2*)(boff + SCAN_B);          //   800,000 int2

    hipMemsetAsync(deg, 0, N_ENT * sizeof(int), stream);

    // projections (ent + rel in one launch)
    proj_kernel<<<ENT_BLKS + REL_BLKS, PROJ_TPB, 0, stream>>>(entity_emb, rel_emb,
                                                              W, ent, rel);

    // CSR build: degree -> 3-kernel parallel scan -> fill
    degree_kernel<<<(N_EDGE + 255) / 256, 256, 0, stream>>>(h_idx, deg);
    scan1_kernel<<<NBLK_SCAN, SCAN_B, 0, stream>>>(deg, bsum);
    scan2_kernel<<<1, SCAN_B, 0, stream>>>(bsum, boff);
    scan3_kernel<<<NBLK_SCAN, SCAN_B, 0, stream>>>(deg, boff, rowptr, cursor);
    fill_kernel<<<(N_EDGE + 255) / 256, 256, 0, stream>>>(h_idx, t_idx, edge_type,
                                                          cursor, tr_sorted);

    // fused: one head per 32-lane half-wave (8 heads / 256-thread block)
    fused_kernel<<<N_ENT / 8, 256, 0, stream>>>(ent, rel, rowptr, tr_sorted, out);
}

// Round 13
// 263.004 us; speedup vs baseline: 1.4819x; 1.0113x over previous
//
#include <hip/hip_runtime.h>
#include <math.h>

#define N_ENT  50000
#define N_REL  500
#define N_EDGE 800000
#define D      100
#define ALPHA  0.2f

#define SCAN_B 256
#define NBLK_SCAN ((N_ENT + SCAN_B - 1) / SCAN_B)   // 196

// ---------------------------------------------------------------------------
// K1: Y = X @ W for BOTH ent and rel in one launch; idle threads (t>=200)
// also zero deg[] (replaces the memset dispatch).
// W^T staged in LDS at stride 101 (conflict-free); X tile in LDS.
// ---------------------------------------------------------------------------
#define PROJ_TPB  256
#define PROJ_RPB  50
#define PROJ_RPT  25
#define WT_STRIDE 101
#define ENT_BLKS  (N_ENT / PROJ_RPB)          // 1000
#define REL_BLKS  (N_REL / PROJ_RPB)          // 10

__global__ __launch_bounds__(PROJ_TPB) void proj_kernel(const float* __restrict__ Xe,
                                                        const float* __restrict__ Xr,
                                                        const float* __restrict__ W,
                                                        float* __restrict__ Ye,
                                                        float* __restrict__ Yr,
                                                        int* __restrict__ deg) {
    __shared__ float WT[D * WT_STRIDE];   // 40.4 KB
    __shared__ float Xs[PROJ_RPB * D];    // 20 KB
    int t = threadIdx.x;

    const float* X; float* Y; size_t xbase;
    if (blockIdx.x < ENT_BLKS) {
        X = Xe; Y = Ye; xbase = (size_t)blockIdx.x * PROJ_RPB * D;
    } else {
        X = Xr; Y = Yr; xbase = (size_t)(blockIdx.x - ENT_BLKS) * PROJ_RPB * D;
    }

    for (int i = t; i < D * D; i += PROJ_TPB) {
        int k = i / D, c = i % D;
        WT[c * WT_STRIDE + k] = W[i];
    }
    for (int i = t; i < PROJ_RPB * D; i += PROJ_TPB)
        Xs[i] = X[xbase + i];
    __syncthreads();

    if (t < 200) {
        int c  = t % 100;
        int r0 = (t / 100) * PROJ_RPT;
        const float* wt = &WT[c * WT_STRIDE];
        for (int j = 0; j < PROJ_RPT; j += 5) {
            const float* x0 = &Xs[(r0 + j    ) * D];
            const float* x1 = &Xs[(r0 + j + 1) * D];
            const float* x2 = &Xs[(r0 + j + 2) * D];
            const float* x3 = &Xs[(r0 + j + 3) * D];
            const float* x4 = &Xs[(r0 + j + 4) * D];
            float a0 = 0.f, a1 = 0.f, a2 = 0.f, a3 = 0.f, a4 = 0.f;
            #pragma unroll
            for (int k = 0; k < D; ++k) {
                float w = wt[k];
                a0 = fmaf(x0[k], w, a0);
                a1 = fmaf(x1[k], w, a1);
                a2 = fmaf(x2[k], w, a2);
                a3 = fmaf(x3[k], w, a3);
                a4 = fmaf(x4[k], w, a4);
            }
            Y[xbase + (size_t)(r0 + j    ) * D + c] = a0;
            Y[xbase + (size_t)(r0 + j + 1) * D + c] = a1;
            Y[xbase + (size_t)(r0 + j + 2) * D + c] = a2;
            Y[xbase + (size_t)(r0 + j + 3) * D + c] = a3;
            Y[xbase + (size_t)(r0 + j + 4) * D + c] = a4;
        }
    } else {
        // zero deg[] with the 56 idle threads: 56 * 1010 = 56560 >= 50000
        int j = blockIdx.x * (PROJ_TPB - 200) + (t - 200);
        if (j < N_ENT) deg[j] = 0;
    }
}

// ---------------------------------------------------------------------------
// CSR build: degree count -> 3-kernel parallel scan -> fill buckets
// ---------------------------------------------------------------------------
__global__ void degree_kernel(const int* __restrict__ h_idx, int* __restrict__ deg) {
    int e = blockIdx.x * blockDim.x + threadIdx.x;
    if (e < N_EDGE) atomicAdd(&deg[h_idx[e]], 1);
}

__global__ void scan1_kernel(const int* __restrict__ deg, int* __restrict__ bsum) {
    __shared__ int s[SCAN_B];
    int i = blockIdx.x * SCAN_B + threadIdx.x;
    s[threadIdx.x] = (i < N_ENT) ? deg[i] : 0;
    __syncthreads();
    for (int off = SCAN_B / 2; off; off >>= 1) {
        if (threadIdx.x < off) s[threadIdx.x] += s[threadIdx.x + off];
        __syncthreads();
    }
    if (threadIdx.x == 0) bsum[blockIdx.x] = s[0];
}

__global__ void scan2_kernel(const int* __restrict__ bsum, int* __restrict__ boff) {
    __shared__ int s[SCAN_B];
    int tid = threadIdx.x;
    int v = (tid < NBLK_SCAN) ? bsum[tid] : 0;
    s[tid] = v;
    __syncthreads();
    for (int off = 1; off < SCAN_B; off <<= 1) {
        int x = (tid >= off) ? s[tid - off] : 0;
        __syncthreads();
        s[tid] += x;
        __syncthreads();
    }
    if (tid < NBLK_SCAN) boff[tid] = s[tid] - v;   // exclusive
}

__global__ void scan3_kernel(const int* __restrict__ deg, const int* __restrict__ boff,
                             int* __restrict__ rowptr, int* __restrict__ cursor) {
    __shared__ int s[SCAN_B];
    int tid = threadIdx.x;
    int i = blockIdx.x * SCAN_B + tid;
    int v = (i < N_ENT) ? deg[i] : 0;
    s[tid] = v;
    __syncthreads();
    for (int off = 1; off < SCAN_B; off <<= 1) {
        int x = (tid >= off) ? s[tid - off] : 0;
        __syncthreads();
        s[tid] += x;
        __syncthreads();
    }
    int excl = s[tid] - v + boff[blockIdx.x];
    if (i < N_ENT) { rowptr[i] = excl; cursor[i] = excl; }
    if (i == N_ENT - 1) rowptr[N_ENT] = excl + v;
}

__global__ void fill_kernel(const int* __restrict__ h_idx, const int* __restrict__ t_idx,
                            const int* __restrict__ etype, int* __restrict__ cursor,
                            int2* __restrict__ tr_sorted) {
    int e = blockIdx.x * blockDim.x + threadIdx.x;
    if (e >= N_EDGE) return;
    int h = h_idx[e];
    int pos = atomicAdd(&cursor[h], 1);
    tr_sorted[pos] = make_int2(t_idx[e], etype[e]);
}

// ---------------------------------------------------------------------------
// Fused kernel: one head per 32-lane half-wave, float4 per lane (25 active),
// online softmax with SINGLE exp per edge (one of scale/ex is always 1),
// unroll-by-2 so both edges' gathers issue before either serial chain.
// ---------------------------------------------------------------------------
__device__ __forceinline__ float edge_reduce32(const float4& eh, const float4& v) {
    float dx = eh.x + v.x, dy = eh.y + v.y, dz = eh.z + v.z, dw = eh.w + v.w;
    float s = dx * dx;
    s = fmaf(dy, dy, s);
    s = fmaf(dz, dz, s);
    s = fmaf(dw, dw, s);
    #pragma unroll
    for (int off = 16; off; off >>= 1) s += __shfl_xor(s, off, 32);
    return sqrtf(s);                       // leaky_relu identity (s >= 0)
}

__device__ __forceinline__ void online_update(float sc, const float4& v,
                                              float& m, float& den, float4& acc) {
    // mn = max(m,sc); scale = exp(m-mn); ex = exp(sc-mn).
    // One of the two is exp(0)=1 -> single transcendental.
    float d  = sc - m;
    float e  = __expf(-fabsf(d));
    float scale = (d >= 0.f) ? e : 1.f;
    float ex    = (d >= 0.f) ? 1.f : e;
    m = fmaxf(m, sc);
    den   = den * scale + ex;
    acc.x = acc.x * scale - v.x * ex;
    acc.y = acc.y * scale - v.y * ex;
    acc.z = acc.z * scale - v.z * ex;
    acc.w = acc.w * scale - v.w * ex;
}

__global__ __launch_bounds__(256) void fused_kernel(const float* __restrict__ ent,
                                                    const float* __restrict__ rel,
                                                    const int* __restrict__ rowptr,
                                                    const int2* __restrict__ tr_sorted,
                                                    float* __restrict__ out) {
    int head = blockIdx.x * 8 + (threadIdx.x >> 5);   // 8 half-waves per block
    int lane = threadIdx.x & 31;
    if (head >= N_ENT) return;                        // grid exact: 6250*8
    int beg = rowptr[head], end = rowptr[head + 1];

    float4 eh = make_float4(0.f, 0.f, 0.f, 0.f);
    if (lane < 25) eh = ((const float4*)(ent + (size_t)head * D))[lane];

    float  m   = -INFINITY;
    float  den = 0.f;
    float4 acc = make_float4(0.f, 0.f, 0.f, 0.f);

    int i = beg;
    for (; i + 1 < end; i += 2) {
        int2 e0 = tr_sorted[i];
        int2 e1 = tr_sorted[i + 1];
        float4 v0 = make_float4(0.f, 0.f, 0.f, 0.f);
        float4 v1 = make_float4(0.f, 0.f, 0.f, 0.f);
        if (lane < 25) {
            float4 et0 = ((const float4*)(ent + (size_t)e0.x * D))[lane];
            float4 er0 = ((const float4*)(rel + (size_t)e0.y * D))[lane];
            float4 et1 = ((const float4*)(ent + (size_t)e1.x * D))[lane];
            float4 er1 = ((const float4*)(rel + (size_t)e1.y * D))[lane];
            v0 = make_float4(er0.x - et0.x, er0.y - et0.y, er0.z - et0.z, er0.w - et0.w);
            v1 = make_float4(er1.x - et1.x, er1.y - et1.y, er1.z - et1.z, er1.w - et1.w);
        }
        float sc0 = edge_reduce32(eh, v0);
        float sc1 = edge_reduce32(eh, v1);
        online_update(sc0, v0, m, den, acc);
        online_update(sc1, v1, m, den, acc);
    }
    if (i < end) {
        int2 e0 = tr_sorted[i];
        float4 v = make_float4(0.f, 0.f, 0.f, 0.f);
        if (lane < 25) {
            float4 et = ((const float4*)(ent + (size_t)e0.x * D))[lane];
            float4 er = ((const float4*)(rel + (size_t)e0.y * D))[lane];
            v = make_float4(er.x - et.x, er.y - et.y, er.z - et.z, er.w - et.w);
        }
        float sc = edge_reduce32(eh, v);
        online_update(sc, v, m, den, acc);
    }

    float inv = 1.f / (den + 1e-16f);
    float ox = acc.x * inv, oy = acc.y * inv, oz = acc.z * inv, ow = acc.w * inv;
    ox = ox > 0.f ? ox : expm1f(ox);           // ELU
    oy = oy > 0.f ? oy : expm1f(oy);
    oz = oz > 0.f ? oz : expm1f(oz);
    ow = ow > 0.f ? ow : expm1f(ow);
    if (lane < 25)
        ((float4*)(out + (size_t)head * D))[lane] = make_float4(ox, oy, oz, ow);
}

extern "C" void kernel_launch(void* const* d_in, const int* in_sizes, int n_in,
                              void* d_out, int out_size, void* d_ws, size_t ws_size,
                              hipStream_t stream) {
    const float* entity_emb = (const float*)d_in[0];   // [N_ENT, D]
    const float* rel_emb    = (const float*)d_in[1];   // [N_REL, D]
    const float* W          = (const float*)d_in[2];   // [D, D]
    const int*   edge_index = (const int*)d_in[3];     // [2, N_EDGE]
    const int*   edge_type  = (const int*)d_in[4];     // [N_EDGE]
    float*       out        = (float*)d_out;           // [N_ENT, D]

    const int* h_idx = edge_index;             // row 0: head/destination
    const int* t_idx = edge_index + N_EDGE;    // row 1: tail/source

    // workspace layout (~27 MB)
    float* ent       = (float*)d_ws;                    // 5,000,000 f
    float* rel       = ent + (size_t)N_ENT * D;         //    50,000 f
    int*   deg       = (int*)(rel + (size_t)N_REL * D); //    50,000 i
    int*   rowptr    = deg + N_ENT;                     //    50,001 i
    int*   cursor    = rowptr + (N_ENT + 1);            //    50,000 i
    int*   bsum      = cursor + N_ENT;                  //       256 i
    int*   boff      = bsum + SCAN_B;                   //       256 i
    int2*  tr_sorted = (int2*)(boff + SCAN_B);          //   800,000 int2

    // projections (ent + rel in one launch; idle threads zero deg[])
    proj_kernel<<<ENT_BLKS + REL_BLKS, PROJ_TPB, 0, stream>>>(entity_emb, rel_emb,
                                                              W, ent, rel, deg);

    // CSR build: degree -> 3-kernel parallel scan -> fill
    degree_kernel<<<(N_EDGE + 255) / 256, 256, 0, stream>>>(h_idx, deg);
    scan1_kernel<<<NBLK_SCAN, SCAN_B, 0, stream>>>(deg, bsum);
    scan2_kernel<<<1, SCAN_B, 0, stream>>>(bsum, boff);
    scan3_kernel<<<NBLK_SCAN, SCAN_B, 0, stream>>>(deg, boff, rowptr, cursor);
    fill_kernel<<<(N_EDGE + 255) / 256, 256, 0, stream>>>(h_idx, t_idx, edge_type,
                                                          cursor, tr_sorted);

    // fused: one head per 32-lane half-wave (8 heads / 256-thread block)
    fused_kernel<<<N_ENT / 8, 256, 0, stream>>>(ent, rel, rowptr, tr_sorted, out);
}